// Round 11
// baseline (396.934 us; speedup 1.0000x reference)
//
#include <hip/hip_runtime.h>

// out[s][o] = sum_i x[s][i] * dq(w[o][i]); int4 group quant, group=256, scale=max(absmax/7,1e-9)
// x: [16,4096] f32, w: [14336,4096] f32 (235 MB streamed once), out: [16,14336] f32
//
// R12 = no-LDS structure (R10) + depth-2 rotating w prefetch (R8-verified) + RPW=2.
// R11 post-mortem: launch_bounds(,2) changed NOTHING (VGPR 60, dur 143us) —
// per cdna4_isa §10, gfx950 AGPRs are first-class VALU operands, so the
// arch-VGPR/acc-AGPR split never cost a roundtrip. Theory dead.
// What survives all measurements: nothing saturated (VALU 31%, HBM 10%),
// waves stalled ~69%; R10/R11 consume w-loads in the SAME iteration they
// issue (no prefetch) -> full ~600-900cy latency on the serial path 16x/wave;
// R6 (depth-1 prefetch) measured faster than R10/R11. Occupancy steps
// (64/128/256 regs -> 8/4/2 waves/SIMD) forbid RPW=4+depth-2 (>128 total ->
// 2 waves/SIMD); RPW=2+depth-2 fits ~100 total -> 4 waves/SIMD held, and
// 1792 blocks lift the grid cap 14 -> 16 waves/CU.
//  - RPW=2, NWAVE=4 (256 thr), RPB=8 -> 1792 blocks = 7 queued/CU, 4 resident.
//  - depth-2 consume-at-TOP rotation (verified PASSED R5/R8): load for group
//    G issued in iteration G-2 -> ~2 iters of compute cover.
//  - '#pragma unroll 1' on G-loop (R7: full unroll -> 263 MB scratch spill).
//  - x straight from global (L1-resident 16KB slice/group; 7 MB/CU L1 traffic
//    at RPW=2 — why RPW=1's 14 MB/CU was rejected).
// Watch: WRITE_SIZE ~0.9MB (spill tripwire); VALUBusy 31 -> 55-75 if the
// stall theory is right; dur 143 -> 60-90us.

constexpr int O_DIM  = 14336;
constexpr int I_DIM  = 4096;
constexpr int S_DIM  = 16;
constexpr int GS     = 256;           // quant group size
constexpr int NG     = I_DIM / GS;    // 16 groups
constexpr int RPW    = 2;             // rows per wave
constexpr int NWAVE  = 4;             // waves per block
constexpr int NTHR   = 64 * NWAVE;    // 256
constexpr int RPB    = RPW * NWAVE;   // 8 rows/block -> 1792 blocks

// wave64 max-reduce on the VALU pipe (validated correct in R5..R11 runs):
// 4x row_shr + row_bcast15 + row_bcast31, readlane(63) -> wave-uniform SGPR.
// Inputs >= 0, so bound_ctrl=true zero-fill is identity for max.
__device__ __forceinline__ float wave_max_dpp(float x) {
    int v = __float_as_int(x);
    int t;
    t = __builtin_amdgcn_update_dpp(0, v, 0x111, 0xf, 0xf, true); // row_shr:1
    v = __float_as_int(fmaxf(__int_as_float(v), __int_as_float(t)));
    t = __builtin_amdgcn_update_dpp(0, v, 0x112, 0xf, 0xf, true); // row_shr:2
    v = __float_as_int(fmaxf(__int_as_float(v), __int_as_float(t)));
    t = __builtin_amdgcn_update_dpp(0, v, 0x114, 0xf, 0xf, true); // row_shr:4
    v = __float_as_int(fmaxf(__int_as_float(v), __int_as_float(t)));
    t = __builtin_amdgcn_update_dpp(0, v, 0x118, 0xf, 0xf, true); // row_shr:8
    v = __float_as_int(fmaxf(__int_as_float(v), __int_as_float(t)));
    t = __builtin_amdgcn_update_dpp(0, v, 0x142, 0xf, 0xf, true); // row_bcast:15
    v = __float_as_int(fmaxf(__int_as_float(v), __int_as_float(t)));
    t = __builtin_amdgcn_update_dpp(0, v, 0x143, 0xf, 0xf, true); // row_bcast:31
    v = __float_as_int(fmaxf(__int_as_float(v), __int_as_float(t)));
    return __int_as_float(__builtin_amdgcn_readlane(v, 63));
}

__global__ __launch_bounds__(NTHR)
void qlin_kernel(const float* __restrict__ x,
                 const float* __restrict__ w,
                 float* __restrict__ out)
{
    const int tid  = threadIdx.x;
    const int lane = tid & 63;
    const int wv   = tid >> 6;          // 0..NWAVE-1
    const int row0 = blockIdx.x * RPB + wv * RPW;

    const float* wp = w + (size_t)row0 * I_DIM + lane * 4;
    const float* xp = x + lane * 4;     // + s*I_DIM + G*GS per use

    float acc[RPW][S_DIM];
#pragma unroll
    for (int r = 0; r < RPW; ++r)
#pragma unroll
        for (int s = 0; s < S_DIM; ++s) acc[r][s] = 0.0f;

    // depth-2 prefetch pipeline: wn1 holds group G, wn2 holds group G+1.
    float4 wcur[RPW], wn1[RPW], wn2[RPW];
#pragma unroll
    for (int r = 0; r < RPW; ++r)
        wn1[r] = *reinterpret_cast<const float4*>(wp + (size_t)r * I_DIM);
#pragma unroll
    for (int r = 0; r < RPW; ++r)
        wn2[r] = *reinterpret_cast<const float4*>(wp + (size_t)r * I_DIM + GS);

    // unroll 1: R7 lesson — cross-iteration hoisting of global loads blew the
    // 128-reg occupancy step -> 263 MB scratch spill. Keep the body pinned.
#pragma unroll 1
    for (int G = 0; G < NG; ++G) {
        // rotate: consume oldest at the TOP. wn1's loads were issued 2
        // iterations ago -> their wait is covered by ~2 iters of compute.
#pragma unroll
        for (int r = 0; r < RPW; ++r) { wcur[r] = wn1[r]; wn1[r] = wn2[r]; }

        // issue loads for G+2 (the only VMEM writes to wn2; consumed 2 iters
        // from now).
        if (G + 2 < NG) {
#pragma unroll
            for (int r = 0; r < RPW; ++r)
                wn2[r] = *reinterpret_cast<const float4*>(
                    wp + (size_t)r * I_DIM + (G + 2) * GS);
        }

        // dequant wcur in place; absmax on VALU pipe via DPP.
#pragma unroll
        for (int r = 0; r < RPW; ++r) {
            float4 v = wcur[r];
            float m = fmaxf(fmaxf(fabsf(v.x), fabsf(v.y)),
                            fmaxf(fabsf(v.z), fabsf(v.w)));
            m = wave_max_dpp(m);
            float scale = fmaxf(m * (1.0f / 7.0f), 1e-9f);
            float invs  = 1.0f / scale;
            // clamp provably dead: scale >= absmax/7 => |v*invs| <= 7
            wcur[r].x = rintf(v.x * invs) * scale;
            wcur[r].y = rintf(v.y * invs) * scale;
            wcur[r].z = rintf(v.z * invs) * scale;
            wcur[r].w = rintf(v.w * invs) * scale;
        }

        // FMA: x straight from global (L1-hit; group slice = 16 KB).
        const float* xg = xp + G * GS;
#pragma unroll
        for (int s = 0; s < S_DIM; ++s) {
            float4 xv = *reinterpret_cast<const float4*>(
                &xg[(size_t)s * I_DIM]);
#pragma unroll
            for (int r = 0; r < RPW; ++r) {
                acc[r][s] = fmaf(wcur[r].x, xv.x, acc[r][s]);
                acc[r][s] = fmaf(wcur[r].y, xv.y, acc[r][s]);
                acc[r][s] = fmaf(wcur[r].z, xv.z, acc[r][s]);
                acc[r][s] = fmaf(wcur[r].w, xv.w, acc[r][s]);
            }
        }
    }

    // ---- epilogue: reduce 32 accs across 64 lanes (verified R5/R8/R9) ----
    // step 1: fold the two 32-lane halves; step 2: value-splitting butterfly
    // over 32 slots; lane l (l<32) ends with the sum of a[l], l=(r<<4)|s.
    float a[RPW * S_DIM];
#pragma unroll
    for (int r = 0; r < RPW; ++r)
#pragma unroll
        for (int s = 0; s < S_DIM; ++s) a[(r << 4) | s] = acc[r][s];

#pragma unroll
    for (int j = 0; j < RPW * S_DIM; ++j)
        a[j] += __shfl_xor(a[j], 32, 64);

#pragma unroll
    for (int m = 16; m >= 1; m >>= 1) {
        const bool hi = (lane & m) != 0;
#pragma unroll
        for (int j = 0; j < m; ++j) {
            float snd  = hi ? a[j] : a[j + m];
            float rcv  = __shfl_xor(snd, m, 64);
            float kept = hi ? a[j + m] : a[j];
            a[j] = kept + rcv;
        }
    }
    if (lane < 32) {
        const int r = (lane >> 4) & 1, s = lane & 15;
        out[s * O_DIM + (row0 + r)] = a[0];
    }
}

extern "C" void kernel_launch(void* const* d_in, const int* in_sizes, int n_in,
                              void* d_out, int out_size, void* d_ws, size_t ws_size,
                              hipStream_t stream) {
    const float* x = (const float*)d_in[0];   // 1*16*4096
    const float* w = (const float*)d_in[1];   // 14336*4096
    float* out = (float*)d_out;               // 16*14336
    dim3 grid(O_DIM / RPB);                   // 1792 blocks
    dim3 block(NTHR);                         // 256 = 4 waves
    qlin_kernel<<<grid, block, 0, stream>>>(x, w, out);
}

// Round 12
// 392.867 us; speedup vs baseline: 1.0104x; 1.0104x over previous
//
#include <hip/hip_runtime.h>

// out[s][o] = sum_i x[s][i] * dq(w[o][i]); int4 group quant, group=256, scale=max(absmax/7,1e-9)
// x: [16,4096] f32, w: [14336,4096] f32 (235 MB streamed once), out: [16,14336] f32
//
// R13 = the untested best cell: RPW=4 + no-LDS + depth-1 w prefetch + even grid.
// Measured ranking so far: R6(RPW4+LDS+pf)<=138 ~ R10(RPW4,noLDS,nopf)=142
// < R8(RPW2+LDS+pf)=156 < R9=164 < R12(RPW2,noLDS,pf)=174 < R7(spill)=267.
// Two robust axes: RPW=4 beats RPW=2 everywhere (x-loads+addr VALU per output
// scale 1/RPW: R12's VALUBusy 54% vs R10's 31%); prefetch helps within fixed
// RPW (R6 vs R10). This kernel combines both; single-variable vs R10 (adds
// prefetch) and vs R12 (RPW 2->4).
//  - depth-1 consume-at-top rotation: wcur=wnext at TOP, issue wnext for G+1,
//    dequant+FMA (~900cyc) cover the load. Depth-2 at RPW=4 would need
//    64+48 regs -> >128-reg occupancy step (R7 lesson) — rejected.
//  - NWAVE=2 (128 thr), RPB=8 -> 1792 blocks = exactly 7 blocks/CU even.
//    R10's 896 blocks = 3.5/CU gave half the CUs 14% more work (static tail).
//  - '#pragma unroll 1' on G-loop (R7: full unroll -> 263 MB scratch spill).
//  - x straight from global (L1/L2-resident; LDS variants' barriers+staging
//    measured no better: R6~R10 within noise).
// Watch: WRITE_SIZE ~0.9MB (spill tripwire). If dur ~140 unchanged ->
// prefetch null at RPW=4 -> ~140 is structural (DVFS candidate) -> roofline.

constexpr int O_DIM  = 14336;
constexpr int I_DIM  = 4096;
constexpr int S_DIM  = 16;
constexpr int GS     = 256;           // quant group size
constexpr int NG     = I_DIM / GS;    // 16 groups
constexpr int RPW    = 4;             // rows per wave (measured-best amortization)
constexpr int NWAVE  = 2;             // waves per block (no coupling; grid evenness)
constexpr int NTHR   = 64 * NWAVE;    // 128
constexpr int RPB    = RPW * NWAVE;   // 8 rows/block -> 1792 blocks = 7/CU even

// wave64 max-reduce on the VALU pipe (validated correct in R5..R12 runs):
// 4x row_shr + row_bcast15 + row_bcast31, readlane(63) -> wave-uniform SGPR.
// Inputs >= 0, so bound_ctrl=true zero-fill is identity for max.
__device__ __forceinline__ float wave_max_dpp(float x) {
    int v = __float_as_int(x);
    int t;
    t = __builtin_amdgcn_update_dpp(0, v, 0x111, 0xf, 0xf, true); // row_shr:1
    v = __float_as_int(fmaxf(__int_as_float(v), __int_as_float(t)));
    t = __builtin_amdgcn_update_dpp(0, v, 0x112, 0xf, 0xf, true); // row_shr:2
    v = __float_as_int(fmaxf(__int_as_float(v), __int_as_float(t)));
    t = __builtin_amdgcn_update_dpp(0, v, 0x114, 0xf, 0xf, true); // row_shr:4
    v = __float_as_int(fmaxf(__int_as_float(v), __int_as_float(t)));
    t = __builtin_amdgcn_update_dpp(0, v, 0x118, 0xf, 0xf, true); // row_shr:8
    v = __float_as_int(fmaxf(__int_as_float(v), __int_as_float(t)));
    t = __builtin_amdgcn_update_dpp(0, v, 0x142, 0xf, 0xf, true); // row_bcast:15
    v = __float_as_int(fmaxf(__int_as_float(v), __int_as_float(t)));
    t = __builtin_amdgcn_update_dpp(0, v, 0x143, 0xf, 0xf, true); // row_bcast:31
    v = __float_as_int(fmaxf(__int_as_float(v), __int_as_float(t)));
    return __int_as_float(__builtin_amdgcn_readlane(v, 63));
}

__global__ __launch_bounds__(NTHR)
void qlin_kernel(const float* __restrict__ x,
                 const float* __restrict__ w,
                 float* __restrict__ out)
{
    const int tid  = threadIdx.x;
    const int lane = tid & 63;
    const int wv   = tid >> 6;          // 0..NWAVE-1
    const int row0 = blockIdx.x * RPB + wv * RPW;

    const float* wp = w + (size_t)row0 * I_DIM + lane * 4;
    const float* xp = x + lane * 4;     // + s*I_DIM + G*GS per use

    float acc[RPW][S_DIM];
#pragma unroll
    for (int r = 0; r < RPW; ++r)
#pragma unroll
        for (int s = 0; s < S_DIM; ++s) acc[r][s] = 0.0f;

    // depth-1 prefetch: wnext holds group G's data at the top of iteration G.
    float4 wcur[RPW], wnext[RPW];
#pragma unroll
    for (int r = 0; r < RPW; ++r)
        wnext[r] = *reinterpret_cast<const float4*>(wp + (size_t)r * I_DIM);

    // unroll 1: R7 lesson — cross-iteration hoisting of global loads blew the
    // 128-reg occupancy step -> 263 MB scratch spill. Keep the body pinned.
#pragma unroll 1
    for (int G = 0; G < NG; ++G) {
        // consume at the TOP; wnext was issued one full iteration ago.
#pragma unroll
        for (int r = 0; r < RPW; ++r) wcur[r] = wnext[r];

        // issue loads for G+1 — covered by this iteration's dequant+FMA.
        if (G + 1 < NG) {
#pragma unroll
            for (int r = 0; r < RPW; ++r)
                wnext[r] = *reinterpret_cast<const float4*>(
                    wp + (size_t)r * I_DIM + (G + 1) * GS);
        }

        // dequant wcur in place; absmax on VALU pipe via DPP.
#pragma unroll
        for (int r = 0; r < RPW; ++r) {
            float4 v = wcur[r];
            float m = fmaxf(fmaxf(fabsf(v.x), fabsf(v.y)),
                            fmaxf(fabsf(v.z), fabsf(v.w)));
            m = wave_max_dpp(m);
            float scale = fmaxf(m * (1.0f / 7.0f), 1e-9f);
            float invs  = 1.0f / scale;
            // clamp provably dead: scale >= absmax/7 => |v*invs| <= 7
            wcur[r].x = rintf(v.x * invs) * scale;
            wcur[r].y = rintf(v.y * invs) * scale;
            wcur[r].z = rintf(v.z * invs) * scale;
            wcur[r].w = rintf(v.w * invs) * scale;
        }

        // FMA: x straight from global (coalesced 1KB/instr; group slice 16KB
        // is L1/L2-resident). 16 dwordx4 per iteration.
        const float* xg = xp + G * GS;
#pragma unroll
        for (int s = 0; s < S_DIM; ++s) {
            float4 xv = *reinterpret_cast<const float4*>(
                &xg[(size_t)s * I_DIM]);
#pragma unroll
            for (int r = 0; r < RPW; ++r) {
                acc[r][s] = fmaf(wcur[r].x, xv.x, acc[r][s]);
                acc[r][s] = fmaf(wcur[r].y, xv.y, acc[r][s]);
                acc[r][s] = fmaf(wcur[r].z, xv.z, acc[r][s]);
                acc[r][s] = fmaf(wcur[r].w, xv.w, acc[r][s]);
            }
        }
    }

    // ---- epilogue: reduce 64 accs across 64 lanes in 63 shuffles ----
    // value-splitting butterfly (validated R6/R10/R11); lane l ends with the
    // sum of a[l], l = (r<<4)|s.
    float a[64];
#pragma unroll
    for (int r = 0; r < RPW; ++r)
#pragma unroll
        for (int s = 0; s < S_DIM; ++s) a[(r << 4) | s] = acc[r][s];

#pragma unroll
    for (int m = 32; m >= 1; m >>= 1) {
        const bool hi = (lane & m) != 0;
#pragma unroll
        for (int j = 0; j < m; ++j) {
            float snd  = hi ? a[j] : a[j + m];
            float rcv  = __shfl_xor(snd, m, 64);
            float kept = hi ? a[j + m] : a[j];
            a[j] = kept + rcv;
        }
    }
    {
        const int r = lane >> 4, s = lane & 15;
        out[s * O_DIM + (row0 + r)] = a[0];
    }
}

extern "C" void kernel_launch(void* const* d_in, const int* in_sizes, int n_in,
                              void* d_out, int out_size, void* d_ws, size_t ws_size,
                              hipStream_t stream) {
    const float* x = (const float*)d_in[0];   // 1*16*4096
    const float* w = (const float*)d_in[1];   // 14336*4096
    float* out = (float*)d_out;               // 16*14336
    dim3 grid(O_DIM / RPB);                   // 1792 blocks = 7/CU, even
    dim3 block(NTHR);                         // 128 = 2 waves
    qlin_kernel<<<grid, block, 0, stream>>>(x, w, out);
}

// Round 13
// 336.148 us; speedup vs baseline: 1.1808x; 1.1687x over previous
//
#include <hip/hip_runtime.h>

// out[s][o] = sum_i x[s][i] * dq(w[o][i]); int4 group quant, group=256, scale=max(absmax/7,1e-9)
// x: [16,4096] f32, w: [14336,4096] f32 (235 MB streamed once), out: [16,14336] f32
//
// R14 = EXACT REVERT to R6 (the session-0 inherited kernel), zero code changes.
// Why: harness_dur - kernel_dur is constant ~222us across all passing rounds
// (R7..R13). Applied to R0's 337.3us bench -> R6 kernel ~= 115us, BEST ever
// measured here. Full ranking: R6 ~115 < R10 142 < R8 156 < R9 164 < R13~R12
// ~174 < R7(spill) 267. Every departure from R6 regressed. Pipe reading: R6
// is the only variant splitting x onto the LDS pipe (16 ds_read_b128/iter)
// leaving VMEM/TA to carry just 4 w-loads/iter; no-LDS variants push all 20
// mem-ops through the one L1/TA path (64B/cyc/CU). RPW=2 variants double
// per-output instruction overhead (VALUBusy 54-61%).
// R6's counters were never captured (R0 profile showed only harness fills);
// this round re-establishes the champion AND finally profiles it to pick the
// next single-variable lever:
//   - VALUBusy high -> thin dequant (1.0f/scale is a full-precision div
//     sequence; DPP absmax chain is serial) or raise RPW amortization.
//   - VALUBusy low  -> latency: deepen w prefetch within the 128-reg step.
// Structure (R6): RPW=4, NWAVE=7 (448 thr), PH_I=1024 (64KB LDS, 2 blocks/CU),
// depth-1 w prefetch (issue-at-top, consume-same-iter, swap-at-bottom),
// DPP absmax on VALU pipe, x staged global->reg->LDS per 1024-col phase,
// 64-slot value-splitting butterfly epilogue. 512 blocks = 2/CU.

constexpr int O_DIM  = 14336;
constexpr int I_DIM  = 4096;
constexpr int S_DIM  = 16;
constexpr int GS     = 256;           // quant group size
constexpr int NG     = I_DIM / GS;    // 16 groups
constexpr int RPW    = 4;             // rows per wave
constexpr int NWAVE  = 7;             // waves per block
constexpr int NTHR   = 64 * NWAVE;    // 448
constexpr int RPB    = RPW * NWAVE;   // 28 rows/block -> 512 blocks = 2/CU
constexpr int PH_I   = 1024;          // i-extent per x staging phase
constexpr int NPH    = I_DIM / PH_I;  // 4 phases
constexpr int GPP    = PH_I / GS;     // 4 groups per phase

// wave64 max-reduce on the VALU pipe (validated correct in R5..R13 runs):
// 4x row_shr + row_bcast15 + row_bcast31, readlane(63) -> wave-uniform SGPR.
// Inputs >= 0, so bound_ctrl=true zero-fill is identity for max.
__device__ __forceinline__ float wave_max_dpp(float x) {
    int v = __float_as_int(x);
    int t;
    t = __builtin_amdgcn_update_dpp(0, v, 0x111, 0xf, 0xf, true); // row_shr:1
    v = __float_as_int(fmaxf(__int_as_float(v), __int_as_float(t)));
    t = __builtin_amdgcn_update_dpp(0, v, 0x112, 0xf, 0xf, true); // row_shr:2
    v = __float_as_int(fmaxf(__int_as_float(v), __int_as_float(t)));
    t = __builtin_amdgcn_update_dpp(0, v, 0x114, 0xf, 0xf, true); // row_shr:4
    v = __float_as_int(fmaxf(__int_as_float(v), __int_as_float(t)));
    t = __builtin_amdgcn_update_dpp(0, v, 0x118, 0xf, 0xf, true); // row_shr:8
    v = __float_as_int(fmaxf(__int_as_float(v), __int_as_float(t)));
    t = __builtin_amdgcn_update_dpp(0, v, 0x142, 0xf, 0xf, true); // row_bcast:15
    v = __float_as_int(fmaxf(__int_as_float(v), __int_as_float(t)));
    t = __builtin_amdgcn_update_dpp(0, v, 0x143, 0xf, 0xf, true); // row_bcast:31
    v = __float_as_int(fmaxf(__int_as_float(v), __int_as_float(t)));
    return __int_as_float(__builtin_amdgcn_readlane(v, 63));
}

__global__ __launch_bounds__(NTHR)
void qlin_kernel(const float* __restrict__ x,
                 const float* __restrict__ w,
                 float* __restrict__ out)
{
    __shared__ float xs[S_DIM][PH_I];   // 64 KB -> LDS caps at 2 blocks/CU

    const int tid  = threadIdx.x;
    const int lane = tid & 63;
    const int wv   = tid >> 6;          // 0..6
    const int row0 = blockIdx.x * RPB + wv * RPW;

    const float* wp = w + (size_t)row0 * I_DIM + lane * 4;

    float acc[RPW][S_DIM];
#pragma unroll
    for (int r = 0; r < RPW; ++r)
#pragma unroll
        for (int s = 0; s < S_DIM; ++s) acc[r][s] = 0.0f;

    float4 wcur[RPW], wnext[RPW];
#pragma unroll
    for (int r = 0; r < RPW; ++r)
        wcur[r] = *reinterpret_cast<const float4*>(wp + (size_t)r * I_DIM);

    for (int p = 0; p < NPH; ++p) {
        // ---- stage x[:, p*1024 .. +1024) into LDS (4096 float4 / 448 thr) ----
        if (p) __syncthreads();         // all waves done reading phase p-1
        for (int j = tid; j < S_DIM * (PH_I / 4); j += NTHR) {
            const int s  = j >> 8;          // float4-slot / 256-per-row
            const int i4 = (j & 255) * 4;
            *reinterpret_cast<float4*>(&xs[s][i4]) =
                *reinterpret_cast<const float4*>(
                    &x[(size_t)s * I_DIM + p * PH_I + i4]);
        }
        __syncthreads();

        for (int g = 0; g < GPP; ++g) {
            const int G = p * GPP + g;      // global group index

            // next group's w — the only vmem in the steady loop; consumed next
            // iteration, covered by the dequant+FMA below (~900 cyc).
            if (G + 1 < NG) {
#pragma unroll
                for (int r = 0; r < RPW; ++r)
                    wnext[r] = *reinterpret_cast<const float4*>(
                        wp + (size_t)r * I_DIM + (G + 1) * GS);
            }

            // dequant wcur in place; absmax on VALU pipe via DPP
#pragma unroll
            for (int r = 0; r < RPW; ++r) {
                float4 v = wcur[r];
                float m = fmaxf(fmaxf(fabsf(v.x), fabsf(v.y)),
                                fmaxf(fabsf(v.z), fabsf(v.w)));
                m = wave_max_dpp(m);
                float scale = fmaxf(m * (1.0f / 7.0f), 1e-9f);
                float invs  = 1.0f / scale;
                // clamp provably dead: scale >= absmax/7 => |v*invs| <= 7
                wcur[r].x = rintf(v.x * invs) * scale;
                wcur[r].y = rintf(v.y * invs) * scale;
                wcur[r].z = rintf(v.z * invs) * scale;
                wcur[r].w = rintf(v.w * invs) * scale;
            }

            // FMA: x from LDS (lgkmcnt only — never waits on wnext)
            const int xb = g * GS + lane * 4;
#pragma unroll
            for (int s = 0; s < S_DIM; ++s) {
                float4 xv = *reinterpret_cast<const float4*>(&xs[s][xb]);
#pragma unroll
                for (int r = 0; r < RPW; ++r) {
                    acc[r][s] = fmaf(wcur[r].x, xv.x, acc[r][s]);
                    acc[r][s] = fmaf(wcur[r].y, xv.y, acc[r][s]);
                    acc[r][s] = fmaf(wcur[r].z, xv.z, acc[r][s]);
                    acc[r][s] = fmaf(wcur[r].w, xv.w, acc[r][s]);
                }
            }

#pragma unroll
            for (int r = 0; r < RPW; ++r) wcur[r] = wnext[r];
        }
    }

    // ---- epilogue: reduce 64 accs across 64 lanes in 63 shuffles ----
    // value-splitting butterfly; lane l ends with the sum of a[l], l=(r<<4)|s.
    float a[64];
#pragma unroll
    for (int r = 0; r < RPW; ++r)
#pragma unroll
        for (int s = 0; s < S_DIM; ++s) a[(r << 4) | s] = acc[r][s];

#pragma unroll
    for (int m = 32; m >= 1; m >>= 1) {
        const bool hi = (lane & m) != 0;
#pragma unroll
        for (int j = 0; j < m; ++j) {
            float snd  = hi ? a[j] : a[j + m];
            float rcv  = __shfl_xor(snd, m, 64);
            float kept = hi ? a[j + m] : a[j];
            a[j] = kept + rcv;
        }
    }
    {
        const int r = lane >> 4, s = lane & 15;
        out[s * O_DIM + (row0 + r)] = a[0];
    }
}

extern "C" void kernel_launch(void* const* d_in, const int* in_sizes, int n_in,
                              void* d_out, int out_size, void* d_ws, size_t ws_size,
                              hipStream_t stream) {
    const float* x = (const float*)d_in[0];   // 1*16*4096
    const float* w = (const float*)d_in[1];   // 14336*4096
    float* out = (float*)d_out;               // 16*14336
    dim3 grid(O_DIM / RPB);                   // 512 blocks -> 2 per CU
    dim3 block(NTHR);                         // 448 = 7 waves
    qlin_kernel<<<grid, block, 0, stream>>>(x, w, out);
}